// Round 8
// baseline (309.904 us; speedup 1.0000x reference)
//
#include <hip/hip_runtime.h>
#include <hip/hip_cooperative_groups.h>
#include <cstdint>
#include <cstddef>

namespace cg = cooperative_groups;

typedef unsigned short u16;
typedef __bf16 bf16x8 __attribute__((ext_vector_type(8)));
typedef float floatx4 __attribute__((ext_vector_type(4)));

#define NPTS 4096
#define MGRD 4096
#define DDIM 8

#define AS1 __attribute__((address_space(1)))
#define AS3 __attribute__((address_space(3)))

// round-to-nearest-even fp32 -> bf16
static __device__ __forceinline__ u16 f2bf(float f) {
    uint32_t u = __float_as_uint(f);
    u += 0x7fffu + ((u >> 16) & 1u);
    return (u16)(u >> 16);
}

#define FENCE() asm volatile("" ::: "memory")
static __device__ __forceinline__ void bar() {
    FENCE(); __builtin_amdgcn_s_barrier(); FENCE();
}

// ---------------- R13: single cooperative mega-kernel ----------------
// R11/R12 post-mortem: the 256^2 4-phase port is pathological (~8000 cyc/K-tile
// > pipe-sum 5300); 4 distinct schedules failed to reproduce m201's overlap
// (consistent with learn-loop m232's failed reproduction). GEMM reverts to the
// best verified structure (R10: complementary-pair jobs, single barrier per
// K-tile, triple-buffered LDS, vmcnt(6); 74.2 us, 929 TF effective).
// This round attacks the OTHER ~111 us: dur_us - gemm has been 105-117 us in
// every round, yet prep never shows in rocprof top-5 (prep < 74 us) and prep's
// traffic floor is ~15 us. Fold everything into ONE cooperative dispatch:
//   Phase A: kstar (same verified body; 512 virtual blocks over 256x512 thr)
//   Phase B: tril transpose+convert (same verified body; 2 tiles/block-round)
//   __threadfence + grid.sync()   [harness-supported cooperative launch]
//   Phase C: R10 gemm verbatim (256 blocks, 1/CU -- co-residency guaranteed
//            by 144 KB LDS -> 1 block/CU x 256 CUs)
// Removes one launch + inter-dispatch gap, doubles prep thread count, and
// makes prep cost directly measurable as (dispatch_dur - 74).

__global__ __launch_bounds__(512, 2) void mega_kernel(
    const float* __restrict__ x,    // [4096,8]
    const float* __restrict__ g,    // [4096,8]
    const float* __restrict__ ls,   // [8]
    const float* __restrict__ B,    // [4096,4096] chol_inv fp32
    u16* __restrict__ A,            // ws: k_star bf16 [4096][4096]
    u16* __restrict__ Bt,           // ws: chol_inv^T bf16 [4096][4096]
    float* __restrict__ C)          // out [4096][4096] fp32
{
    // gemm needs 3 x 24576 u16 = 144 KB; prep phase B borrows 33 KB of it
    __shared__ u16 lds[3 * 24576] __attribute__((aligned(16)));

    const int bid = blockIdx.x;     // 0..255
    const int tid = threadIdx.x;    // 0..511

    // ================= Phase A: kstar (verified body) =================
    {
        const int vb = bid * 2 + (tid >> 8);    // virtual block 0..511
        const int t  = tid & 255;
        const int kb = vb & 1;
        const int n0 = (vb >> 1) * 16;
        const int k0 = kb * 2048 + t * 8;       // this thread's 8 grid rows

        float il[DDIM];
#pragma unroll
        for (int d = 0; d < DDIM; ++d) il[d] = 1.0f / ls[d];

        float4 g0[8], g1[8];
#pragma unroll
        for (int r = 0; r < 8; ++r) {
            g0[r] = *reinterpret_cast<const float4*>(g + (size_t)(k0 + r) * DDIM);
            g1[r] = *reinterpret_cast<const float4*>(g + (size_t)(k0 + r) * DDIM + 4);
        }

        for (int nn = 0; nn < 16; ++nn) {
            const int n = n0 + nn;
            const float4 x0 = *reinterpret_cast<const float4*>(x + (size_t)n * DDIM);
            const float4 x1 = *reinterpret_cast<const float4*>(x + (size_t)n * DDIM + 4);
            alignas(16) u16 res[8];
#pragma unroll
            for (int r = 0; r < 8; ++r) {
                float s = fabsf(x0.x - g0[r].x) * il[0] + fabsf(x0.y - g0[r].y) * il[1]
                        + fabsf(x0.z - g0[r].z) * il[2] + fabsf(x0.w - g0[r].w) * il[3]
                        + fabsf(x1.x - g1[r].x) * il[4] + fabsf(x1.y - g1[r].y) * il[5]
                        + fabsf(x1.z - g1[r].z) * il[6] + fabsf(x1.w - g1[r].w) * il[7];
                res[r] = f2bf(__expf(-s));
            }
            *reinterpret_cast<uint4*>(A + (size_t)n * MGRD + k0) =
                *reinterpret_cast<const uint4*>(res);
        }
    }

    // ============ Phase B: tril transpose+convert (verified body) ============
    {
        float* tf = reinterpret_cast<float*>(lds) + (tid >> 8) * 4160;  // [64][65]
        const int t = tid & 255;
#pragma unroll 1
        for (int r = 0; r < 8; ++r) {
            const int idt = bid * 16 + r * 2 + (tid >> 8);   // 0..4095
            const int bx = idt & 63;         // m-tile
            const int by = idt >> 6;         // k-tile
            const bool act = (by >= (bx & ~1));   // tiles the 128-wide gemm reads
            const int k0 = by * 64;
            const int m0 = bx * 64;

            __syncthreads();                 // tf reuse across r-iterations
            if (act) {
#pragma unroll
                for (int rr = 0; rr < 4; ++rr) {
                    int c   = rr * 256 + t;
                    int row = c >> 4;
                    int col = (c & 15) * 4;
                    const float4 v = *reinterpret_cast<const float4*>(
                        &B[(size_t)(k0 + row) * MGRD + m0 + col]);
                    tf[row * 65 + col + 0] = v.x; tf[row * 65 + col + 1] = v.y;
                    tf[row * 65 + col + 2] = v.z; tf[row * 65 + col + 3] = v.w;
                }
            }
            __syncthreads();
            if (act) {
#pragma unroll
                for (int rr = 0; rr < 2; ++rr) {
                    int c  = rr * 256 + t;
                    int mr = c >> 3;
                    int kc = (c & 7) * 8;
                    alignas(16) u16 tmp[8];
#pragma unroll
                    for (int j = 0; j < 8; ++j)
                        tmp[j] = f2bf(tf[(kc + j) * 65 + mr]);
                    *reinterpret_cast<uint4*>(&Bt[(size_t)(m0 + mr) * MGRD + k0 + kc]) =
                        *reinterpret_cast<const uint4*>(tmp);
                }
            }
        }
    }

    // ============ grid-wide sync: prep outputs -> gemm inputs ============
    __threadfence();
    cg::this_grid().sync();

    // ================= Phase C: gemm (R10 verbatim, verified) =================
    const int lane = tid & 63;
    const int w    = tid >> 6;          // 0..7
    const int kg   = w >> 2;            // K-slice group: 0 -> k[0:32), 1 -> k[32:64)
    const int wq   = w & 3;
    const int nq   = wq >> 1;           // n-half: 128 rows
    const int mq   = wq & 1;            // m-half: 64 cols
    const int lrow = lane & 15;
    const int lhi  = lane >> 4;         // 0..3
    const int r7   = lrow & 7;

    const int id  = bid;                // 0..255
    const int bm1 = id >> 4;            // 0..15 (job1; job2 = 31-bm1)
    const int bn  = id & 15;
    const int bn0 = bn << 8;            // 256-row n tile (same for both jobs)

    const int arow = tid >> 3;                       // 0..63
    const int aswz = ((tid ^ arow) & 7) * 8;
    int aoff[4];
#pragma unroll
    for (int r = 0; r < 4; ++r)
        aoff[r] = (bn0 + r * 64 + arow) * 4096 + aswz;

    const int ldst = w * 512;           // wave chunk (elems) within inst region
    const int cswz = ((kg * 4 + lhi) ^ r7) * 8;      // verified read-side swizzle
    const int rowA = (nq * 128 + lrow) * 64 + cswz;
    const int rowB = (mq * 64  + lrow) * 64 + cswz;

#define STG_A(QA, R, K) __builtin_amdgcn_global_load_lds(                        \
    (const AS1 void*)(A + (size_t)aoff[R] + (K)),                                \
    (AS3 void*)((QA) + (R) * 4096 + ldst), 16, 0, 0)
#define STG_B(QB, R, K) __builtin_amdgcn_global_load_lds(                        \
    (const AS1 void*)(Bt + (size_t)boff[R] + (K)),                               \
    (AS3 void*)((QB) + (R) * 4096 + ldst), 16, 0, 0)

    bf16x8 af[8], bfv[4];
    floatx4 acc[8][4];

#define MF(a, b, c) __builtin_amdgcn_mfma_f32_16x16x32_bf16(a, b, c, 0, 0, 0)
#define MFMA32() do {                                                            \
    __builtin_amdgcn_s_setprio(1);                                               \
    _Pragma("unroll")                                                            \
    for (int i_ = 0; i_ < 8; ++i_)                                               \
        _Pragma("unroll")                                                        \
        for (int j_ = 0; j_ < 4; ++j_)                                           \
            acc[i_][j_] = MF(af[i_], bfv[j_], acc[i_][j_]);                      \
    __builtin_amdgcn_s_setprio(0);                                               \
} while (0)

#define REGION(PA, PB, QA, QB, KST) do {                                         \
    STG_A(QA, 0, KST); STG_A(QA, 1, KST);                                        \
    af[0]  = *reinterpret_cast<const bf16x8*>((PA) + rowA + 0 * 1024);           \
    bfv[0] = *reinterpret_cast<const bf16x8*>((PB) + rowB + 0 * 1024);           \
    bfv[1] = *reinterpret_cast<const bf16x8*>((PB) + rowB + 1 * 1024);           \
    bfv[2] = *reinterpret_cast<const bf16x8*>((PB) + rowB + 2 * 1024);           \
    bfv[3] = *reinterpret_cast<const bf16x8*>((PB) + rowB + 3 * 1024);           \
    STG_A(QA, 2, KST); STG_A(QA, 3, KST);                                        \
    af[1]  = *reinterpret_cast<const bf16x8*>((PA) + rowA + 1 * 1024);           \
    af[2]  = *reinterpret_cast<const bf16x8*>((PA) + rowA + 2 * 1024);           \
    af[3]  = *reinterpret_cast<const bf16x8*>((PA) + rowA + 3 * 1024);           \
    STG_B(QB, 0, KST); STG_B(QB, 1, KST);                                        \
    af[4]  = *reinterpret_cast<const bf16x8*>((PA) + rowA + 4 * 1024);           \
    af[5]  = *reinterpret_cast<const bf16x8*>((PA) + rowA + 5 * 1024);           \
    af[6]  = *reinterpret_cast<const bf16x8*>((PA) + rowA + 6 * 1024);           \
    af[7]  = *reinterpret_cast<const bf16x8*>((PA) + rowA + 7 * 1024);           \
    MFMA32();                                                                    \
} while (0)

#define RDALL(PA, PB) do {                                                       \
    af[0]  = *reinterpret_cast<const bf16x8*>((PA) + rowA + 0 * 1024);           \
    bfv[0] = *reinterpret_cast<const bf16x8*>((PB) + rowB + 0 * 1024);           \
    bfv[1] = *reinterpret_cast<const bf16x8*>((PB) + rowB + 1 * 1024);           \
    bfv[2] = *reinterpret_cast<const bf16x8*>((PB) + rowB + 2 * 1024);           \
    bfv[3] = *reinterpret_cast<const bf16x8*>((PB) + rowB + 3 * 1024);           \
    af[1]  = *reinterpret_cast<const bf16x8*>((PA) + rowA + 1 * 1024);           \
    af[2]  = *reinterpret_cast<const bf16x8*>((PA) + rowA + 2 * 1024);           \
    af[3]  = *reinterpret_cast<const bf16x8*>((PA) + rowA + 3 * 1024);           \
    af[4]  = *reinterpret_cast<const bf16x8*>((PA) + rowA + 4 * 1024);           \
    af[5]  = *reinterpret_cast<const bf16x8*>((PA) + rowA + 5 * 1024);           \
    af[6]  = *reinterpret_cast<const bf16x8*>((PA) + rowA + 6 * 1024);           \
    af[7]  = *reinterpret_cast<const bf16x8*>((PA) + rowA + 7 * 1024);           \
} while (0)

    for (int jj = 0; jj < 2; ++jj) {
        const int bm  = jj ? (31 - bm1) : bm1;
        const int bm0 = bm << 7;        // 128-row m tile
        const int L   = 64 - 2 * bm;    // K-tiles, even, >= 2

        int boff[2];
#pragma unroll
        for (int r = 0; r < 2; ++r)
            boff[r] = (bm0 + r * 64 + arow) * 4096 + aswz;

#pragma unroll
        for (int i = 0; i < 8; ++i)
#pragma unroll
            for (int j = 0; j < 4; ++j)
                acc[i][j] = (floatx4)0.0f;

        // ---- prologue: stage tiles 0,1 (reverse-K: tile T at k = 4032-64T) ----
        int kT = 4096 - 64;             // k of tile currently computed
        {
            u16* qA0 = lds;             u16* qB0 = lds + 16384;
            u16* qA1 = lds + 24576;     u16* qB1 = lds + 24576 + 16384;
            STG_A(qA0, 0, kT); STG_A(qA0, 1, kT); STG_A(qA0, 2, kT); STG_A(qA0, 3, kT);
            STG_B(qB0, 0, kT); STG_B(qB0, 1, kT);
            STG_A(qA1, 0, kT - 64); STG_A(qA1, 1, kT - 64);
            STG_A(qA1, 2, kT - 64); STG_A(qA1, 3, kT - 64);
            STG_B(qB1, 0, kT - 64); STG_B(qB1, 1, kT - 64);
        }
        asm volatile("s_waitcnt vmcnt(6)" ::: "memory");   // tile 0 landed
        bar();

        // ---- main loop: single region per K-tile, one barrier ----
        int p = 0;
        for (int T = 0; T < L - 2; ++T) {
            u16* pA = lds + p * 24576;  u16* pB = pA + 16384;
            int p2 = p + 2; if (p2 >= 3) p2 -= 3;
            u16* qA = lds + p2 * 24576; u16* qB = qA + 16384;

            REGION(pA, pB, qA, qB, kT - 128);
            asm volatile("s_waitcnt vmcnt(6)" ::: "memory");  // tile T+1 landed
            bar();

            kT -= 64; ++p; if (p == 3) p = 0;
        }

        // ---- peel T = L-2 (no staging; drain last tile) ----
        {
            u16* pA = lds + p * 24576;  u16* pB = pA + 16384;
            RDALL(pA, pB);
            MFMA32();
            asm volatile("s_waitcnt vmcnt(0)" ::: "memory");  // tile L-1 landed
            bar();
            ++p; if (p == 3) p = 0;
        }
        // ---- peel T = L-1 ----
        {
            u16* pA = lds + p * 24576;  u16* pB = pA + 16384;
            RDALL(pA, pB);
            MFMA32();
        }

        // ---- epilogue: cross-kg reduce via LDS scratch, then store (verified) ----
        __syncthreads();                // all LDS tile reads done; reuse as scratch
        float* scr = reinterpret_cast<float*>(lds);   // 4 x 32 KB = 128 KB used
        if (kg == 1) {
#pragma unroll
            for (int i = 0; i < 8; ++i)
#pragma unroll
                for (int j = 0; j < 4; ++j)
                    *reinterpret_cast<floatx4*>(
                        scr + (size_t)wq * 8192 + (i * 4 + j) * 256 + lane * 4) = acc[i][j];
        }
        __syncthreads();
        if (kg == 0) {
#pragma unroll
            for (int i = 0; i < 8; ++i)
#pragma unroll
                for (int j = 0; j < 4; ++j)
                    acc[i][j] += *reinterpret_cast<const floatx4*>(
                        scr + (size_t)wq * 8192 + (i * 4 + j) * 256 + lane * 4);

            // C/D layout: col = lane&15 (m), row = (lane>>4)*4 + reg (n)  [m89]
#pragma unroll
            for (int i = 0; i < 8; ++i) {
                int rown = bn0 + nq * 128 + i * 16 + lhi * 4;
#pragma unroll
                for (int j = 0; j < 4; ++j) {
                    int colm = bm0 + mq * 64 + j * 16 + lrow;
                    float* cp = C + (size_t)rown * 4096 + colm;
#pragma unroll
                    for (int rr = 0; rr < 4; ++rr)
                        cp[(size_t)rr * 4096] = acc[i][j][rr];
                }
            }
        }
        __syncthreads();                // scr reads + stores retired; LDS free for job 2
    }
}

extern "C" void kernel_launch(void* const* d_in, const int* in_sizes, int n_in,
                              void* d_out, int out_size, void* d_ws, size_t ws_size,
                              hipStream_t stream)
{
    const float* x    = (const float*)d_in[0];   // [4096,8]
    const float* grid = (const float*)d_in[1];   // [4096,8]
    const float* ci   = (const float*)d_in[2];   // [4096,4096]
    const float* ls   = (const float*)d_in[3];   // [8]
    float* out = (float*)d_out;                  // [4096,4096] fp32

    u16* wsA  = (u16*)d_ws;                            // k_star bf16, 33.5 MB
    u16* wsBt = (u16*)d_ws + (size_t)MGRD * MGRD;      // chol_inv^T bf16, 33.5 MB

    void* args[7];
    args[0] = (void*)&x;
    args[1] = (void*)&grid;
    args[2] = (void*)&ls;
    args[3] = (void*)&ci;
    args[4] = (void*)&wsA;
    args[5] = (void*)&wsBt;
    args[6] = (void*)&out;

    hipLaunchCooperativeKernel((const void*)mega_kernel, dim3(256), dim3(512),
                               args, 0, stream);
}

// Round 9
// 184.655 us; speedup vs baseline: 1.6783x; 1.6783x over previous
//
#include <hip/hip_runtime.h>
#include <cstdint>
#include <cstddef>

typedef unsigned short u16;
typedef __bf16 bf16x8 __attribute__((ext_vector_type(8)));
typedef float floatx4 __attribute__((ext_vector_type(4)));

#define NPTS 4096
#define MGRD 4096
#define DDIM 8

// round-to-nearest-even fp32 -> bf16
static __device__ __forceinline__ u16 f2bf(float f) {
    uint32_t u = __float_as_uint(f);
    u += 0x7fffu + ((u >> 16) & 1u);
    return (u16)(u >> 16);
}

// ---------------- Fused prep (verified) ----------------
__global__ __launch_bounds__(256) void prep_kernel(
    const float* __restrict__ x, const float* __restrict__ g,
    const float* __restrict__ ls, const float* __restrict__ B,
    u16* __restrict__ A, u16* __restrict__ Bt)
{
    __shared__ float tile[64][65];
    const int bid = blockIdx.x;
    const int tid = threadIdx.x;

    if (bid < 512) {
        const int kb = bid & 1;
        const int n0 = (bid >> 1) * 16;
        const int k0 = kb * 2048 + tid * 8;

        float il[DDIM];
#pragma unroll
        for (int d = 0; d < DDIM; ++d) il[d] = 1.0f / ls[d];

        float4 g0[8], g1[8];
#pragma unroll
        for (int r = 0; r < 8; ++r) {
            g0[r] = *reinterpret_cast<const float4*>(g + (size_t)(k0 + r) * DDIM);
            g1[r] = *reinterpret_cast<const float4*>(g + (size_t)(k0 + r) * DDIM + 4);
        }

        for (int nn = 0; nn < 16; ++nn) {
            const int n = n0 + nn;
            const float4 x0 = *reinterpret_cast<const float4*>(x + (size_t)n * DDIM);
            const float4 x1 = *reinterpret_cast<const float4*>(x + (size_t)n * DDIM + 4);
            alignas(16) u16 res[8];
#pragma unroll
            for (int r = 0; r < 8; ++r) {
                float s = fabsf(x0.x - g0[r].x) * il[0] + fabsf(x0.y - g0[r].y) * il[1]
                        + fabsf(x0.z - g0[r].z) * il[2] + fabsf(x0.w - g0[r].w) * il[3]
                        + fabsf(x1.x - g1[r].x) * il[4] + fabsf(x1.y - g1[r].y) * il[5]
                        + fabsf(x1.z - g1[r].z) * il[6] + fabsf(x1.w - g1[r].w) * il[7];
                res[r] = f2bf(__expf(-s));
            }
            *reinterpret_cast<uint4*>(A + (size_t)n * MGRD + k0) =
                *reinterpret_cast<const uint4*>(res);
        }
    } else {
        const int id = bid - 512;
        const int bx = id & 63;
        const int by = id >> 6;
        if (by < (bx & ~1)) return;
        const int k0 = by * 64;
        const int m0 = bx * 64;

#pragma unroll
        for (int r = 0; r < 4; ++r) {
            int c   = r * 256 + tid;
            int row = c >> 4;
            int col = (c & 15) * 4;
            const float4 v = *reinterpret_cast<const float4*>(&B[(size_t)(k0 + row) * MGRD + m0 + col]);
            tile[row][col + 0] = v.x; tile[row][col + 1] = v.y;
            tile[row][col + 2] = v.z; tile[row][col + 3] = v.w;
        }
        __syncthreads();

#pragma unroll
        for (int r = 0; r < 2; ++r) {
            int c  = r * 256 + tid;
            int mr = c >> 3;
            int kc = (c & 7) * 8;
            alignas(16) u16 tmp[8];
#pragma unroll
            for (int j = 0; j < 8; ++j)
                tmp[j] = f2bf(tile[kc + j][mr]);
            *reinterpret_cast<uint4*>(&Bt[(size_t)(m0 + mr) * MGRD + k0 + kc]) =
                *reinterpret_cast<const uint4*>(tmp);
        }
    }
}

// ---------------- R10 (verified best, 74.2 us): complementary-pair jobs ----------------
// Each block runs TWO jobs (bm, 31-bm) at the same bn: L(bm)+L(31-bm) = 66 for
// all bm -> every CU exactly 66 K-tile units, zero tail. Inner loop: single
// barrier per K-tile, direct consume, triple-buffered LDS, vmcnt(6) per tile
// (never 0 in loop), stage issues interleaved among ds_reads. 8 waves =
// 2kg x 2nq x 2mq, per-wave 128n x 64m at one 32-wide K-slice; cross-kg
// partial sums reduced via LDS scratch in the epilogue.

#define FENCE() asm volatile("" ::: "memory")
static __device__ __forceinline__ void bar() {
    FENCE(); __builtin_amdgcn_s_barrier(); FENCE();
}

__global__ __launch_bounds__(512, 2) void gemm_pair_kernel(
    const u16* __restrict__ A,    // [4096][4096] bf16 (n-major, k contiguous)
    const u16* __restrict__ Bt,   // [4096][4096] bf16 (m-major, k contiguous)
    float* __restrict__ C)        // [4096][4096] fp32
{
    // 3 x (A 256x64 + B 128x64) bf16 = 3 x 48 KB = 144 KB
    __shared__ u16 lds[3 * 24576] __attribute__((aligned(16)));

    const int tid  = threadIdx.x;
    const int lane = tid & 63;
    const int w    = tid >> 6;          // 0..7
    const int kg   = w >> 2;            // K-slice group: 0 -> k[0:32), 1 -> k[32:64)
    const int wq   = w & 3;
    const int nq   = wq >> 1;           // n-half: 128 rows
    const int mq   = wq & 1;            // m-half: 64 cols
    const int lrow = lane & 15;
    const int lhi  = lane >> 4;         // 0..3
    const int r7   = lrow & 7;

    const int id  = blockIdx.x;         // 0..255
    const int bm1 = id >> 4;            // 0..15 (job1; job2 = 31-bm1)
    const int bn  = id & 15;
    const int bn0 = bn << 8;            // 256-row n tile (same for both jobs)

    // ---- A staging source offsets (bn-only; constant across jobs) ----
    const int arow = tid >> 3;                       // 0..63
    const int aswz = ((tid ^ arow) & 7) * 8;
    int aoff[4];
#pragma unroll
    for (int r = 0; r < 4; ++r)
        aoff[r] = (bn0 + r * 64 + arow) * 4096 + aswz;

    const int ldst = w * 512;           // wave chunk (elems) within inst region
    const int cswz = ((kg * 4 + lhi) ^ r7) * 8;      // verified read-side swizzle
    const int rowA = (nq * 128 + lrow) * 64 + cswz;
    const int rowB = (mq * 64  + lrow) * 64 + cswz;

#define STG_A(QA, R, K) __builtin_amdgcn_global_load_lds(                        \
    (const __attribute__((address_space(1))) void*)(A + (size_t)aoff[R] + (K)),  \
    (__attribute__((address_space(3))) void*)((QA) + (R) * 4096 + ldst), 16, 0, 0)
#define STG_B(QB, R, K) __builtin_amdgcn_global_load_lds(                        \
    (const __attribute__((address_space(1))) void*)(Bt + (size_t)boff[R] + (K)), \
    (__attribute__((address_space(3))) void*)((QB) + (R) * 4096 + ldst), 16, 0, 0)

    bf16x8 af[8], bfv[4];

    floatx4 acc[8][4];

#define MF(a, b, c) __builtin_amdgcn_mfma_f32_16x16x32_bf16(a, b, c, 0, 0, 0)
#define MFMA32() do {                                                            \
    __builtin_amdgcn_s_setprio(1);                                               \
    _Pragma("unroll")                                                            \
    for (int i_ = 0; i_ < 8; ++i_)                                               \
        _Pragma("unroll")                                                        \
        for (int j_ = 0; j_ < 4; ++j_)                                           \
            acc[i_][j_] = MF(af[i_], bfv[j_], acc[i_][j_]);                      \
    __builtin_amdgcn_s_setprio(0);                                               \
} while (0)

    // region body: stage 6 loads for tile T+2 interleaved with 12 ds_reads of
    // tile T (read order af0,b0..b3,af1..af7: first MFMA ready after 5 reads)
#define REGION(PA, PB, QA, QB, KST) do {                                         \
    STG_A(QA, 0, KST); STG_A(QA, 1, KST);                                        \
    af[0]  = *reinterpret_cast<const bf16x8*>((PA) + rowA + 0 * 1024);           \
    bfv[0] = *reinterpret_cast<const bf16x8*>((PB) + rowB + 0 * 1024);           \
    bfv[1] = *reinterpret_cast<const bf16x8*>((PB) + rowB + 1 * 1024);           \
    bfv[2] = *reinterpret_cast<const bf16x8*>((PB) + rowB + 2 * 1024);           \
    bfv[3] = *reinterpret_cast<const bf16x8*>((PB) + rowB + 3 * 1024);           \
    STG_A(QA, 2, KST); STG_A(QA, 3, KST);                                        \
    af[1]  = *reinterpret_cast<const bf16x8*>((PA) + rowA + 1 * 1024);           \
    af[2]  = *reinterpret_cast<const bf16x8*>((PA) + rowA + 2 * 1024);           \
    af[3]  = *reinterpret_cast<const bf16x8*>((PA) + rowA + 3 * 1024);           \
    STG_B(QB, 0, KST); STG_B(QB, 1, KST);                                        \
    af[4]  = *reinterpret_cast<const bf16x8*>((PA) + rowA + 4 * 1024);           \
    af[5]  = *reinterpret_cast<const bf16x8*>((PA) + rowA + 5 * 1024);           \
    af[6]  = *reinterpret_cast<const bf16x8*>((PA) + rowA + 6 * 1024);           \
    af[7]  = *reinterpret_cast<const bf16x8*>((PA) + rowA + 7 * 1024);           \
    MFMA32();                                                                    \
} while (0)

#define RDALL(PA, PB) do {                                                       \
    af[0]  = *reinterpret_cast<const bf16x8*>((PA) + rowA + 0 * 1024);           \
    bfv[0] = *reinterpret_cast<const bf16x8*>((PB) + rowB + 0 * 1024);           \
    bfv[1] = *reinterpret_cast<const bf16x8*>((PB) + rowB + 1 * 1024);           \
    bfv[2] = *reinterpret_cast<const bf16x8*>((PB) + rowB + 2 * 1024);           \
    bfv[3] = *reinterpret_cast<const bf16x8*>((PB) + rowB + 3 * 1024);           \
    af[1]  = *reinterpret_cast<const bf16x8*>((PA) + rowA + 1 * 1024);           \
    af[2]  = *reinterpret_cast<const bf16x8*>((PA) + rowA + 2 * 1024);           \
    af[3]  = *reinterpret_cast<const bf16x8*>((PA) + rowA + 3 * 1024);           \
    af[4]  = *reinterpret_cast<const bf16x8*>((PA) + rowA + 4 * 1024);           \
    af[5]  = *reinterpret_cast<const bf16x8*>((PA) + rowA + 5 * 1024);           \
    af[6]  = *reinterpret_cast<const bf16x8*>((PA) + rowA + 6 * 1024);           \
    af[7]  = *reinterpret_cast<const bf16x8*>((PA) + rowA + 7 * 1024);           \
} while (0)

    for (int jj = 0; jj < 2; ++jj) {
        const int bm  = jj ? (31 - bm1) : bm1;
        const int bm0 = bm << 7;        // 128-row m tile
        const int L   = 64 - 2 * bm;    // K-tiles, even, >= 2

        // ---- B staging source offsets for this job ----
        int boff[2];
#pragma unroll
        for (int r = 0; r < 2; ++r)
            boff[r] = (bm0 + r * 64 + arow) * 4096 + aswz;

#pragma unroll
        for (int i = 0; i < 8; ++i)
#pragma unroll
            for (int j = 0; j < 4; ++j)
                acc[i][j] = (floatx4)0.0f;

        // ---- prologue: stage tiles 0,1 (reverse-K: tile T at k = 4032-64T) ----
        int kT = 4096 - 64;             // k of tile currently computed
        {
            u16* qA0 = lds;             u16* qB0 = lds + 16384;
            u16* qA1 = lds + 24576;     u16* qB1 = lds + 24576 + 16384;
            STG_A(qA0, 0, kT); STG_A(qA0, 1, kT); STG_A(qA0, 2, kT); STG_A(qA0, 3, kT);
            STG_B(qB0, 0, kT); STG_B(qB0, 1, kT);
            STG_A(qA1, 0, kT - 64); STG_A(qA1, 1, kT - 64);
            STG_A(qA1, 2, kT - 64); STG_A(qA1, 3, kT - 64);
            STG_B(qB1, 0, kT - 64); STG_B(qB1, 1, kT - 64);
        }
        asm volatile("s_waitcnt vmcnt(6)" ::: "memory");   // tile 0 landed
        bar();

        // ---- main loop: single region per K-tile, one barrier ----
        int p = 0;
        for (int T = 0; T < L - 2; ++T) {
            u16* pA = lds + p * 24576;  u16* pB = pA + 16384;
            int p2 = p + 2; if (p2 >= 3) p2 -= 3;
            u16* qA = lds + p2 * 24576; u16* qB = qA + 16384;

            REGION(pA, pB, qA, qB, kT - 128);
            asm volatile("s_waitcnt vmcnt(6)" ::: "memory");  // tile T+1 landed
            bar();

            kT -= 64; ++p; if (p == 3) p = 0;
        }

        // ---- peel T = L-2 (no staging; drain last tile) ----
        {
            u16* pA = lds + p * 24576;  u16* pB = pA + 16384;
            RDALL(pA, pB);
            MFMA32();
            asm volatile("s_waitcnt vmcnt(0)" ::: "memory");  // tile L-1 landed
            bar();
            ++p; if (p == 3) p = 0;
        }
        // ---- peel T = L-1 ----
        {
            u16* pA = lds + p * 24576;  u16* pB = pA + 16384;
            RDALL(pA, pB);
            MFMA32();
        }

        // ---- epilogue: cross-kg reduce via LDS scratch, then store (verified) ----
        __syncthreads();                // all LDS tile reads done; reuse as scratch
        float* scr = reinterpret_cast<float*>(lds);   // 4 x 32 KB = 128 KB used
        if (kg == 1) {
#pragma unroll
            for (int i = 0; i < 8; ++i)
#pragma unroll
                for (int j = 0; j < 4; ++j)
                    *reinterpret_cast<floatx4*>(
                        scr + (size_t)wq * 8192 + (i * 4 + j) * 256 + lane * 4) = acc[i][j];
        }
        __syncthreads();
        if (kg == 0) {
#pragma unroll
            for (int i = 0; i < 8; ++i)
#pragma unroll
                for (int j = 0; j < 4; ++j)
                    acc[i][j] += *reinterpret_cast<const floatx4*>(
                        scr + (size_t)wq * 8192 + (i * 4 + j) * 256 + lane * 4);

            // C/D layout: col = lane&15 (m), row = (lane>>4)*4 + reg (n)  [m89]
#pragma unroll
            for (int i = 0; i < 8; ++i) {
                int rown = bn0 + nq * 128 + i * 16 + lhi * 4;
#pragma unroll
                for (int j = 0; j < 4; ++j) {
                    int colm = bm0 + mq * 64 + j * 16 + lrow;
                    float* cp = C + (size_t)rown * 4096 + colm;
#pragma unroll
                    for (int rr = 0; rr < 4; ++rr)
                        cp[(size_t)rr * 4096] = acc[i][j][rr];
                }
            }
        }
        __syncthreads();                // scr reads + stores retired; LDS free for job 2
    }
}

extern "C" void kernel_launch(void* const* d_in, const int* in_sizes, int n_in,
                              void* d_out, int out_size, void* d_ws, size_t ws_size,
                              hipStream_t stream)
{
    const float* x    = (const float*)d_in[0];   // [4096,8]
    const float* grid = (const float*)d_in[1];   // [4096,8]
    const float* ci   = (const float*)d_in[2];   // [4096,4096]
    const float* ls   = (const float*)d_in[3];   // [8]
    float* out = (float*)d_out;                  // [4096,4096] fp32

    u16* wsA  = (u16*)d_ws;                            // k_star bf16, 33.5 MB
    u16* wsBt = (u16*)d_ws + (size_t)MGRD * MGRD;      // chol_inv^T bf16, 33.5 MB

    prep_kernel<<<dim3(512 + 64 * 64), 256, 0, stream>>>(x, grid, ls, ci, wsA, wsBt);
    gemm_pair_kernel<<<dim3(256), 512, 0, stream>>>(wsA, wsBt, out);
}